// Round 22
// baseline (171.988 us; speedup 1.0000x reference)
//
#include <hip/hip_runtime.h>
#include <math.h>

#define NODES 50000
#define NEDGE 800000
#define ETOT  (NEDGE + NODES)   // edges + self loops = 850000
#define NF    256
#define F1    128               // HEADS*NHID
#define NHEAD 8
#define NHID  16
#define NC    40
#define ELLCAP 64               // slots per dst; P(deg>63) ~ 1e-17 for Poisson(16)
#define NBINS 391               // ceil(NODES/128); bin = d>>7
#define BINSTR 400              // counter/segment stride per residue
#define SUBCAP 512              // per (bin,residue) capacity; mean ~272, 14 sigma
// fused scatter+gemm1 grid: 3321 scatter blocks + 782 gemm blocks, 4:1 interleave
#define SG_BLOCKS 4103
#define SG_GEMMCUT 3910         // 782*5; gemm role at bid%5==4 below this

typedef __attribute__((ext_vector_type(8))) short bf16x8;
typedef __attribute__((ext_vector_type(4))) float f32x4;
typedef __attribute__((ext_vector_type(2))) float f32x2;

__device__ __forceinline__ float bflo(unsigned u) { return __uint_as_float(u << 16); }
__device__ __forceinline__ float bfhi(unsigned u) { return __uint_as_float(u & 0xffff0000u); }
__device__ __forceinline__ unsigned short f2bf(float f) {
    unsigned u = __float_as_uint(f);
    unsigned r = u + 0x7fffu + ((u >> 16) & 1u);   // RNE
    return (unsigned short)(r >> 16);
}
__device__ __forceinline__ unsigned pk2(float a, float b) {
    return (unsigned)f2bf(a) | ((unsigned)f2bf(b) << 16);
}
__device__ __forceinline__ unsigned char f2fp8(float v) {
    return (unsigned char)(__builtin_amdgcn_cvt_pk_fp8_f32(v, v, 0, false) & 0xff);
}

// ---------- prep (merged): W1t144[144][256] + W2e[48][128], both bf16 ----------
__global__ void prepW12(const float* __restrict__ W1, const float* __restrict__ atts1,
                        const float* __restrict__ attd1,
                        const float* __restrict__ W2, const float* __restrict__ atts2,
                        const float* __restrict__ attd2,
                        unsigned short* __restrict__ W1t, unsigned short* __restrict__ W2e) {
    int b = blockIdx.x;
    int k = threadIdx.x;
    if (b < 144) {
        int n = b;            // 0..143, k 0..255
        float v;
        if (n < 128) {
            v = W1[(size_t)k * F1 + n];
        } else if (n < 136) {
            int h = n - 128; v = 0.f;
#pragma unroll
            for (int c = 0; c < 16; ++c) v += W1[(size_t)k * F1 + h * 16 + c] * atts1[h * 16 + c];
        } else {
            int h = n - 136; v = 0.f;
#pragma unroll
            for (int c = 0; c < 16; ++c) v += W1[(size_t)k * F1 + h * 16 + c] * attd1[h * 16 + c];
        }
        W1t[(size_t)n * NF + k] = f2bf(v);
    } else {
        int n = b - 144;      // 0..47, k valid 0..127
        if (k >= F1) return;
        float v = 0.f;
        if (n < NC) {
            v = W2[(size_t)k * NC + n];
        } else if (n == NC) {
#pragma unroll
            for (int c = 0; c < NC; ++c) v += W2[(size_t)k * NC + c] * atts2[c];
        } else if (n == NC + 1) {
#pragma unroll
            for (int c = 0; c < NC; ++c) v += W2[(size_t)k * NC + c] * attd2[c];
        }
        W2e[(size_t)n * F1 + k] = f2bf(v);
    }
}

// ---------- FUSED: binning pass-1 (XCD-sharded appends) + MFMA GEMM1 ----------
__global__ __launch_bounds__(256) void scatter_gemm1(
        const unsigned* __restrict__ u,
        int* __restrict__ binCnt, unsigned* __restrict__ binBuf,
        const float* __restrict__ x, const unsigned short* __restrict__ W1t,
        unsigned char* __restrict__ h1f8, float* __restrict__ as1,
        float* __restrict__ ad1) {
    __shared__ uint4 wlds[1152];         // 144 rows x 8 uint4 = 18432 B
    int bid = blockIdx.x;
    int t = threadIdx.x;
    bool isGemm = (bid < SG_GEMMCUT) && ((bid % 5) == 4);
    if (!isGemm) {
        // ---- pass-1 role: append edge to (bin, residue) segment ----
        // self-detect edge dtype: int64 data has zero hi-words at odd slots.
        unsigned hw = u[2 * (t & 63) + 1];
        bool isi32 = __ballot(hw != 0) != 0;
        int si = bid - min(bid, SG_GEMMCUT) / 5;   // gemm blocks before bid
        int e = si * 256 + t;
        if (e >= ETOT) return;
        int s, d;
        if (e < NEDGE) {
            if (isi32) { s = (int)u[e]; d = (int)u[NEDGE + e]; }
            else       { s = (int)u[2 * e]; d = (int)u[2 * NEDGE + 2 * e]; }
        } else s = d = e - NEDGE;
        int res = bid & 7;               // presumed XCD id (perf heuristic only)
        int idx = res * BINSTR + (d >> 7);
        int pos = atomicAdd(&binCnt[idx], 1);
        if (pos < SUBCAP)
            binBuf[((size_t)idx << 9) + pos] = ((unsigned)s << 7) | (unsigned)(d & 127);
        return;
    }
    // ---- gemm role (4-quarter LDS staging, 18.4 KB) ----
    int gi = bid / 5;
    int wave = t >> 6, lane = t & 63;
    int mbase = gi * 64 + wave * 16;
    int rowc = min(mbase + (lane & 15), NODES - 1);
    int kg = lane >> 4;              // 0..3
    const float4* xr = (const float4*)(x + (size_t)rowc * NF + kg * 8);

    float4 xa[16];
#pragma unroll
    for (int ks = 0; ks < 8; ++ks) {
        xa[2 * ks]     = xr[ks * 8];
        xa[2 * ks + 1] = xr[ks * 8 + 1];
    }
    __builtin_amdgcn_sched_barrier(0);   // pin x loads before staging

    f32x4 acc[9];
#pragma unroll
    for (int f = 0; f < 9; ++f) acc[f] = (f32x4){0.f, 0.f, 0.f, 0.f};

    int r = lane & 15;
    int rsw = r & 7;

#pragma unroll
    for (int q = 0; q < 4; ++q) {
        if (q) __syncthreads();
#pragma unroll
        for (int it = 0; it < 5; ++it) {
            int i = it * 256 + t;
            if (i < 1152) {
                int row = i >> 3, s = i & 7;
                wlds[row * 8 + (s ^ (row & 7))] = ((const uint4*)W1t)[row * 32 + q * 8 + s];
            }
        }
        __syncthreads();
#pragma unroll
        for (int ks2 = 0; ks2 < 2; ++ks2) {
            int ks = q * 2 + ks2;
            union { uint4 u4; bf16x8 v; } A;
            float4 a0 = xa[2 * ks], a1 = xa[2 * ks + 1];
            A.u4.x = pk2(a0.x, a0.y); A.u4.y = pk2(a0.z, a0.w);
            A.u4.z = pk2(a1.x, a1.y); A.u4.w = pk2(a1.z, a1.w);
#pragma unroll
            for (int f = 0; f < 9; ++f) {
                union { uint4 u4; bf16x8 v; } B;
                B.u4 = wlds[f * 128 + r * 8 + ((ks2 * 4 + kg) ^ rsw)];
                acc[f] = __builtin_amdgcn_mfma_f32_16x16x32_bf16(A.v, B.v, acc[f], 0, 0, 0);
            }
        }
    }

    int col = lane & 15;
    int rbase = mbase + (lane >> 4) * 4;
#pragma unroll
    for (int f = 0; f < 8; ++f) {
        int wv = 0;
        wv = __builtin_amdgcn_cvt_pk_fp8_f32(acc[f][0], acc[f][1], wv, false);
        wv = __builtin_amdgcn_cvt_pk_fp8_f32(acc[f][2], acc[f][3], wv, true);
#pragma unroll
        for (int ii = 0; ii < 4; ++ii) {
            int rr = rbase + ii;
            if (rr < NODES)
                h1f8[(size_t)rr * F1 + f * 16 + col] = (unsigned char)((wv >> (8 * ii)) & 0xff);
        }
    }
#pragma unroll
    for (int ii = 0; ii < 4; ++ii) {
        int rr = rbase + ii;
        if (rr < NODES) {
            float v = acc[8][ii];
            if (col < 8) as1[(size_t)rr * NHEAD + col] = v;
            else ad1[(size_t)rr * NHEAD + (col - 8)] = v;
        }
    }
}

// ---------- pass-2: LDS scatter within bin + coalesced csr16/fill writes ----------
__global__ __launch_bounds__(256) void binfix(const int* __restrict__ binCnt,
                                              const unsigned* __restrict__ binBuf,
                                              unsigned short* __restrict__ csr16,
                                              int* __restrict__ fill) {
    __shared__ unsigned short rows[128][ELLCAP];   // 16 KB
    __shared__ int cnt[128];
    int b = blockIdx.x, t = threadIdx.x;
    if (t < 128) cnt[t] = 0;
    __syncthreads();
#pragma unroll
    for (int res = 0; res < 8; ++res) {
        int idx = res * BINSTR + b;
        int n = min(binCnt[idx], SUBCAP);
        const unsigned* seg = binBuf + ((size_t)idx << 9);
        for (int j = t; j < n; j += 256) {
            unsigned w = seg[j];
            int dl = w & 127;
            int p = atomicAdd(&cnt[dl], 1);
            if (p < ELLCAP) rows[dl][p] = (unsigned short)(w >> 7);
        }
    }
    __syncthreads();
    int d0 = b * 128;
    // 128 rows x 128 B = 1024 uint4, coalesced
    for (int i = t; i < 1024; i += 256) {
        int row = i >> 3, q = i & 7;
        int d = d0 + row;
        if (d < NODES)
            *(uint4*)(csr16 + ((size_t)d << 6) + q * 8) = *(const uint4*)(&rows[row][q * 8]);
    }
    if (t < 128 && d0 + t < NODES) fill[d0 + t] = min(cnt[t], ELLCAP);
}

// no-max softmax step, fp8 h-row (8 channels per lane)
#define PROC8F8(AV, HV)                                          \
    {                                                            \
        float l = (AV) + adv;                                    \
        l = l > 0.f ? l : 0.2f * l;                              \
        float p = __expf(l);                                     \
        den += p;                                                \
        f32x2 c0 = __builtin_amdgcn_cvt_pk_f32_fp8(HV.x, false); \
        f32x2 c1 = __builtin_amdgcn_cvt_pk_f32_fp8(HV.x, true);  \
        f32x2 c2 = __builtin_amdgcn_cvt_pk_f32_fp8(HV.y, false); \
        f32x2 c3 = __builtin_amdgcn_cvt_pk_f32_fp8(HV.y, true);  \
        acc[0] += p * c0.x; acc[1] += p * c0.y;                  \
        acc[2] += p * c1.x; acc[3] += p * c1.y;                  \
        acc[4] += p * c2.x; acc[5] += p * c2.y;                  \
        acc[6] += p * c3.x; acc[7] += p * c3.y;                  \
    }

// ---------- L1 gather + fused GEMM2: block owns 16 dst (M=16 tile) ----------
__global__ __launch_bounds__(256) void msg1g2(const int* __restrict__ fill,
                                              const unsigned short* __restrict__ csr16,
                                              const float* __restrict__ as1,
                                              const float* __restrict__ ad1,
                                              const unsigned char* __restrict__ h1f8,
                                              const float* __restrict__ b1,
                                              const unsigned short* __restrict__ W2e,
                                              unsigned char* __restrict__ h2f8,
                                              float* __restrict__ as2,
                                              float* __restrict__ ad2) {
    __shared__ uint4 w2s[768];           // 48 x 16 uint4 = 12 KB, swizzled
    __shared__ uint4 o1s[256];           // 16 rows x 16 uint4 = 4 KB, swizzled
    int t = threadIdx.x;
    int wid = t >> 6, lane = t & 63;
    int g = lane >> 4;                    // group 0..3 -> own dst
    int cl = lane & 15;                   // channel lane: ch 8*cl..8*cl+7
    int h = cl >> 1;                      // head

#pragma unroll
    for (int it = 0; it < 3; ++it) {
        int i = it * 256 + t;
        w2s[i ^ ((i >> 4) & 7)] = ((const uint4*)W2e)[i];
    }

    int d = blockIdx.x * 16 + wid * 4 + g;   // grid exact: 3125*16 = 50000
    float adv = ad1[(size_t)d * NHEAD + h];
    int deg = fill[d];                        // >= 1 (self loop)
    size_t eb = (size_t)d << 6;               // ELL row base
    float den = 0.f;
    float acc[8];
#pragma unroll
    for (int k = 0; k < 8; ++k) acc[k] = 0.f;

    const char* as1c = (const char*)as1;
    unsigned hoff = (unsigned)(h << 2);
    unsigned coff = (unsigned)(cl << 3);

// internal index j_ avoids shadowing the caller's loop variable (R11 bug)
#define LD1(J, AV, HV)                                                \
    {                                                                 \
        int j_ = (J);                                                 \
        AV = -1e30f; HV = make_uint2(0u, 0u);                         \
        if (j_ < deg) {                                               \
            unsigned ss = (unsigned)csr16[eb + j_];                   \
            AV = *(const float*)(as1c + (ss << 5) + hoff);            \
            HV = *(const uint2*)(h1f8 + (ss << 7) + coff);            \
        }                                                             \
    }

    float av0, av1; uint2 hv0, hv1;
    LD1(0, av0, hv0);
    LD1(1, av1, hv1);
    for (int j = 0; j < deg; j += 2) {
        float ta, tb; uint2 ua, ub;
        LD1(j + 2, ta, ua);
        LD1(j + 3, tb, ub);
        PROC8F8(av0, hv0);
        PROC8F8(av1, hv1);
        av0 = ta; hv0 = ua; av1 = tb; hv1 = ub;
    }
#undef LD1

    float invd = 1.f / (den + 1e-16f);
    const float4* bp = (const float4*)(b1 + cl * 8);
    float4 ba = bp[0], bb = bp[1];
    float v[8];
    v[0] = acc[0] * invd + ba.x; v[1] = acc[1] * invd + ba.y;
    v[2] = acc[2] * invd + ba.z; v[3] = acc[3] * invd + ba.w;
    v[4] = acc[4] * invd + bb.x; v[5] = acc[5] * invd + bb.y;
    v[6] = acc[6] * invd + bb.z; v[7] = acc[7] * invd + bb.w;
#pragma unroll
    for (int k = 0; k < 8; ++k) {
        float ev = __expf(v[k]) - 1.f;          // ELU negative branch
        v[k] = v[k] > 0.f ? v[k] : ev;
    }
    uint4 o;
    o.x = pk2(v[0], v[1]); o.y = pk2(v[2], v[3]);
    o.z = pk2(v[4], v[5]); o.w = pk2(v[6], v[7]);
    int orow = wid * 4 + g;
    o1s[(orow * 16 + cl) ^ (orow & 7)] = o;
    __syncthreads();

    // Phase 2: GEMM tile f = wid (waves 0..2), M=16 block dst, N=16, K=128
    if (wid < 3) {
        int r = lane & 15;
        int kg = lane >> 4;
        int swz = r & 7;
        f32x4 c2 = (f32x4){0.f, 0.f, 0.f, 0.f};
#pragma unroll
        for (int ks = 0; ks < 4; ++ks) {
            union { uint4 u; bf16x8 vv; } A, B;
            A.u = o1s[(r * 16 + kg + ks * 4) ^ swz];
            B.u = w2s[(wid * 256 + r * 16 + kg + ks * 4) ^ swz];
            c2 = __builtin_amdgcn_mfma_f32_16x16x32_bf16(A.vv, B.vv, c2, 0, 0, 0);
        }
        int col = lane & 15;
        int rbase = blockIdx.x * 16 + (lane >> 4) * 4;
        if (wid < 2) {
#pragma unroll
            for (int i = 0; i < 4; ++i)
                h2f8[(size_t)(rbase + i) * NC + wid * 16 + col] = f2fp8(c2[i]);
        } else {
            int c = 32 + col;
#pragma unroll
            for (int i = 0; i < 4; ++i) {
                int rr = rbase + i;
                if (c < NC) h2f8[(size_t)rr * NC + c] = f2fp8(c2[i]);
                else if (c == NC) as2[rr] = c2[i];
                else if (c == NC + 1) ad2[rr] = c2[i];
            }
        }
    }
}

// ---------- L2 gather: 8-lane group per dst (8 dst/wave), ELL, fp8 h2, depth-2 ----------
__global__ __launch_bounds__(256) void msg2(const int* __restrict__ fill,
                                            const unsigned short* __restrict__ csr16,
                                            const float* __restrict__ as2,
                                            const float* __restrict__ ad2,
                                            const unsigned char* __restrict__ h2f8,
                                            const float* __restrict__ b2,
                                            float* __restrict__ out) {
    int t = threadIdx.x;
    int wid = t >> 6, lane = t & 63;
    int g = lane >> 3;                    // group 0..7 -> own dst
    int cl = lane & 7;                    // channel lane; active cl<5 (8 ch each)
    int clc = cl < 5 ? cl : 4;
    bool act = cl < 5;
    int d0 = blockIdx.x * 32 + wid * 8 + g;
    int d = min(d0, NODES - 1);
    float adv = ad2[d];
    int deg = act ? fill[d] : 0;          // inactive lanes: no loads, no loop
    size_t eb = (size_t)d << 6;
    float den = 0.f;
    float acc[8];
#pragma unroll
    for (int k = 0; k < 8; ++k) acc[k] = 0.f;

    const char* as2c = (const char*)as2;
    unsigned coff = (unsigned)(clc << 3);

#define LD2(J, AV, HV)                                                \
    {                                                                 \
        int j_ = (J);                                                 \
        AV = -1e30f; HV = make_uint2(0u, 0u);                         \
        if (j_ < deg) {                                               \
            unsigned ss = (unsigned)csr16[eb + j_];                   \
            AV = *(const float*)(as2c + (ss << 2));                   \
            HV = *(const uint2*)(h2f8 + ss * 40u + coff);             \
        }                                                             \
    }

    float av0, av1; uint2 hv0, hv1;
    LD2(0, av0, hv0);
    LD2(1, av1, hv1);
    for (int j = 0; j < deg; j += 2) {
        float ta, tb; uint2 ua, ub;
        LD2(j + 2, ta, ua);
        LD2(j + 3, tb, ub);
        PROC8F8(av0, hv0);
        PROC8F8(av1, hv1);
        av0 = ta; hv0 = ua; av1 = tb; hv1 = ub;
    }
#undef LD2

    float invd = 1.f / (den + 1e-16f);
    float v[8];
    float mk = -1e30f;
    if (act) {
        const float4* bp = (const float4*)(b2 + cl * 8);
        float4 ba = bp[0], bb = bp[1];
        v[0] = acc[0] * invd + ba.x; v[1] = acc[1] * invd + ba.y;
        v[2] = acc[2] * invd + ba.z; v[3] = acc[3] * invd + ba.w;
        v[4] = acc[4] * invd + bb.x; v[5] = acc[5] * invd + bb.y;
        v[6] = acc[6] * invd + bb.z; v[7] = acc[7] * invd + bb.w;
#pragma unroll
        for (int k = 0; k < 8; ++k) mk = fmaxf(mk, v[k]);
    }
    // reduce within the 8-lane group
    mk = fmaxf(mk, __shfl_xor(mk, 1, 64));
    mk = fmaxf(mk, __shfl_xor(mk, 2, 64));
    mk = fmaxf(mk, __shfl_xor(mk, 4, 64));
    float e = 0.f;
    if (act) {
#pragma unroll
        for (int k = 0; k < 8; ++k) e += __expf(v[k] - mk);
    }
    e += __shfl_xor(e, 1, 64);
    e += __shfl_xor(e, 2, 64);
    e += __shfl_xor(e, 4, 64);
    float lse = mk + logf(e);
    if (act && d0 < NODES) {
        float4 o0 = make_float4(v[0] - lse, v[1] - lse, v[2] - lse, v[3] - lse);
        float4 o1 = make_float4(v[4] - lse, v[5] - lse, v[6] - lse, v[7] - lse);
        float* po = out + (size_t)d0 * NC + cl * 8;
        *(float4*)po = o0;
        *(float4*)(po + 4) = o1;
    }
}

extern "C" void kernel_launch(void* const* d_in, const int* in_sizes, int n_in,
                              void* d_out, int out_size, void* d_ws, size_t ws_size,
                              hipStream_t stream) {
    const float* x       = (const float*)d_in[0];
    const unsigned* eidx = (const unsigned*)d_in[1];
    const float* W1      = (const float*)d_in[2];
    const float* atts1   = (const float*)d_in[3];
    const float* attd1   = (const float*)d_in[4];
    const float* b1      = (const float*)d_in[5];
    const float* W2      = (const float*)d_in[6];
    const float* atts2   = (const float*)d_in[7];
    const float* attd2   = (const float*)d_in[8];
    const float* b2      = (const float*)d_in[9];
    float* out = (float*)d_out;

    char* base = (char*)d_ws;
    size_t off = 0;
    auto takeB = [&](size_t bytes) {
        void* p = base + off;
        off = (off + bytes + 255) & ~(size_t)255;
        return p;
    };
    int* binCnt    = (int*)takeB((size_t)8 * BINSTR * 4);
    unsigned* binBuf = (unsigned*)takeB((size_t)8 * BINSTR * SUBCAP * 4);
    int* fill      = (int*)takeB((size_t)NODES * 4);
    unsigned short* csr16 = (unsigned short*)takeB((size_t)NODES * ELLCAP * 2 + 256);
    unsigned short* W1t  = (unsigned short*)takeB((size_t)144 * NF * 2);
    unsigned short* W2e  = (unsigned short*)takeB((size_t)48 * F1 * 2);
    unsigned char* h1f8  = (unsigned char*)takeB((size_t)NODES * F1);
    float* as1     = (float*)takeB((size_t)NODES * NHEAD * 4);
    float* ad1     = (float*)takeB((size_t)NODES * NHEAD * 4);
    unsigned char* h2f8  = (unsigned char*)takeB((size_t)NODES * NC + 256);
    float* as2     = (float*)takeB((size_t)NODES * 4);
    float* ad2     = (float*)takeB((size_t)NODES * 4);

    hipMemsetAsync(binCnt, 0, (size_t)8 * BINSTR * 4, stream);

    // weight prep (both layers, one dispatch)
    prepW12<<<192, 256, 0, stream>>>(W1, atts1, attd1, W2, atts2, attd2, W1t, W2e);

    // fused: edge binning pass-1 (XCD-sharded appends) + layer-1 MFMA GEMM
    scatter_gemm1<<<SG_BLOCKS, 256, 0, stream>>>(eidx, binCnt, binBuf,
                                                 x, W1t, h1f8, as1, ad1);

    // pass-2: LDS scatter per 128-dst bin -> coalesced csr16 + fill
    binfix<<<NBINS, 256, 0, stream>>>(binCnt, binBuf, csr16, fill);

    // Layer-1 gather + fused layer-2 projection (out1 stays on-chip)
    msg1g2<<<NODES / 16, 256, 0, stream>>>(fill, csr16, as1, ad1, h1f8, b1,
                                           W2e, h2f8, as2, ad2);

    // Layer-2 gather + log_softmax
    msg2<<<(NODES + 31) / 32, 256, 0, stream>>>(fill, csr16, as2, ad2, h2f8, b2, out);
}

// Round 23
// 114.365 us; speedup vs baseline: 1.5039x; 1.5039x over previous
//
#include <hip/hip_runtime.h>
#include <math.h>

#define NODES 50000
#define NEDGE 800000
#define ETOT  (NEDGE + NODES)   // edges + self loops = 850000
#define NF    256
#define F1    128               // HEADS*NHID
#define NHEAD 8
#define NHID  16
#define NC    40
#define ELLCAP 64               // slots per dst; P(deg>63) ~ 1e-17 for Poisson(16)
// fused scatter+gemm1 grid: 3321 scatter blocks + 782 gemm blocks, 4:1 interleave
#define SG_BLOCKS 4103
#define SG_GEMMCUT 3910         // 782*5; gemm role at bid%5==4 below this

typedef __attribute__((ext_vector_type(8))) short bf16x8;
typedef __attribute__((ext_vector_type(4))) float f32x4;
typedef __attribute__((ext_vector_type(2))) float f32x2;

__device__ __forceinline__ float bflo(unsigned u) { return __uint_as_float(u << 16); }
__device__ __forceinline__ float bfhi(unsigned u) { return __uint_as_float(u & 0xffff0000u); }
__device__ __forceinline__ unsigned short f2bf(float f) {
    unsigned u = __float_as_uint(f);
    unsigned r = u + 0x7fffu + ((u >> 16) & 1u);   // RNE
    return (unsigned short)(r >> 16);
}
__device__ __forceinline__ unsigned pk2(float a, float b) {
    return (unsigned)f2bf(a) | ((unsigned)f2bf(b) << 16);
}
__device__ __forceinline__ unsigned char f2fp8(float v) {
    return (unsigned char)(__builtin_amdgcn_cvt_pk_fp8_f32(v, v, 0, false) & 0xff);
}

// ---------- prep (merged): W1t144[144][256] + W2e[48][128], both bf16 ----------
__global__ void prepW12(const float* __restrict__ W1, const float* __restrict__ atts1,
                        const float* __restrict__ attd1,
                        const float* __restrict__ W2, const float* __restrict__ atts2,
                        const float* __restrict__ attd2,
                        unsigned short* __restrict__ W1t, unsigned short* __restrict__ W2e) {
    int b = blockIdx.x;
    int k = threadIdx.x;
    if (b < 144) {
        int n = b;            // 0..143, k 0..255
        float v;
        if (n < 128) {
            v = W1[(size_t)k * F1 + n];
        } else if (n < 136) {
            int h = n - 128; v = 0.f;
#pragma unroll
            for (int c = 0; c < 16; ++c) v += W1[(size_t)k * F1 + h * 16 + c] * atts1[h * 16 + c];
        } else {
            int h = n - 136; v = 0.f;
#pragma unroll
            for (int c = 0; c < 16; ++c) v += W1[(size_t)k * F1 + h * 16 + c] * attd1[h * 16 + c];
        }
        W1t[(size_t)n * NF + k] = f2bf(v);
    } else {
        int n = b - 144;      // 0..47, k valid 0..127
        if (k >= F1) return;
        float v = 0.f;
        if (n < NC) {
            v = W2[(size_t)k * NC + n];
        } else if (n == NC) {
#pragma unroll
            for (int c = 0; c < NC; ++c) v += W2[(size_t)k * NC + c] * atts2[c];
        } else if (n == NC + 1) {
#pragma unroll
            for (int c = 0; c < NC; ++c) v += W2[(size_t)k * NC + c] * attd2[c];
        }
        W2e[(size_t)n * F1 + k] = f2bf(v);
    }
}

// ---------- FUSED: ELL scatter (self-detecting dtype) + MFMA GEMM1 ----------
// Gemm role stages W1t in FOUR 18.4KB K-quarters -> static LDS 18432 B.
__global__ __launch_bounds__(256) void scatter_gemm1(
        const unsigned* __restrict__ u,
        int* __restrict__ fill, unsigned short* __restrict__ csr16,
        const float* __restrict__ x, const unsigned short* __restrict__ W1t,
        unsigned char* __restrict__ h1f8, float* __restrict__ as1,
        float* __restrict__ ad1) {
    __shared__ uint4 wlds[1152];         // 144 rows x 8 uint4 = 18432 B
    int bid = blockIdx.x;
    int t = threadIdx.x;
    bool isGemm = (bid < SG_GEMMCUT) && ((bid % 5) == 4);
    if (!isGemm) {
        // ---- scatter role: 1 edge per thread, 2B ELL stores ----
        // self-detect edge dtype: int64 data has zero hi-words at odd slots;
        // int32 data has random node ids there (P(all 64 == 0) ~ 0).
        unsigned hw = u[2 * (t & 63) + 1];
        bool isi32 = __ballot(hw != 0) != 0;
        int si = bid - min(bid, SG_GEMMCUT) / 5;   // gemm blocks before bid
        int e = si * 256 + t;
        if (e >= ETOT) return;
        int s, d;
        if (e < NEDGE) {
            if (isi32) { s = (int)u[e]; d = (int)u[NEDGE + e]; }
            else       { s = (int)u[2 * e]; d = (int)u[2 * NEDGE + 2 * e]; }
        } else s = d = e - NEDGE;
        int pos = atomicAdd(&fill[d], 1);
        if (pos < ELLCAP) csr16[((size_t)d << 6) + pos] = (unsigned short)s;
        return;
    }
    // ---- gemm role ----
    int gi = bid / 5;
    int wave = t >> 6, lane = t & 63;
    int mbase = gi * 64 + wave * 16;
    int rowc = min(mbase + (lane & 15), NODES - 1);
    int kg = lane >> 4;              // 0..3
    const float4* xr = (const float4*)(x + (size_t)rowc * NF + kg * 8);

    // issue the full K-strip loads (16 independent dwordx4 in flight)
    float4 xa[16];
#pragma unroll
    for (int ks = 0; ks < 8; ++ks) {
        xa[2 * ks]     = xr[ks * 8];
        xa[2 * ks + 1] = xr[ks * 8 + 1];
    }
    __builtin_amdgcn_sched_barrier(0);   // pin x loads before staging

    f32x4 acc[9];
#pragma unroll
    for (int f = 0; f < 9; ++f) acc[f] = (f32x4){0.f, 0.f, 0.f, 0.f};

    int r = lane & 15;
    int rsw = r & 7;

    // four K-quarters: stage 18.4KB ([144][8] uint4, XOR-swizzled), 2 MFMA steps
#pragma unroll
    for (int q = 0; q < 4; ++q) {
        if (q) __syncthreads();          // all reads of previous quarter done
#pragma unroll
        for (int it = 0; it < 5; ++it) {
            int i = it * 256 + t;
            if (i < 1152) {
                int row = i >> 3, s = i & 7;
                wlds[row * 8 + (s ^ (row & 7))] = ((const uint4*)W1t)[row * 32 + q * 8 + s];
            }
        }
        __syncthreads();
#pragma unroll
        for (int ks2 = 0; ks2 < 2; ++ks2) {
            int ks = q * 2 + ks2;
            union { uint4 u4; bf16x8 v; } A;
            float4 a0 = xa[2 * ks], a1 = xa[2 * ks + 1];
            A.u4.x = pk2(a0.x, a0.y); A.u4.y = pk2(a0.z, a0.w);
            A.u4.z = pk2(a1.x, a1.y); A.u4.w = pk2(a1.z, a1.w);
#pragma unroll
            for (int f = 0; f < 9; ++f) {
                union { uint4 u4; bf16x8 v; } B;
                B.u4 = wlds[f * 128 + r * 8 + ((ks2 * 4 + kg) ^ rsw)];
                acc[f] = __builtin_amdgcn_mfma_f32_16x16x32_bf16(A.v, B.v, acc[f], 0, 0, 0);
            }
        }
    }

    // store: C/D layout col=lane&15, row=(lane>>4)*4+reg; h1 as fp8 e4m3
    int col = lane & 15;
    int rbase = mbase + (lane >> 4) * 4;
#pragma unroll
    for (int f = 0; f < 8; ++f) {
        int wv = 0;
        wv = __builtin_amdgcn_cvt_pk_fp8_f32(acc[f][0], acc[f][1], wv, false);
        wv = __builtin_amdgcn_cvt_pk_fp8_f32(acc[f][2], acc[f][3], wv, true);
#pragma unroll
        for (int ii = 0; ii < 4; ++ii) {
            int rr = rbase + ii;
            if (rr < NODES)
                h1f8[(size_t)rr * F1 + f * 16 + col] = (unsigned char)((wv >> (8 * ii)) & 0xff);
        }
    }
#pragma unroll
    for (int ii = 0; ii < 4; ++ii) {
        int rr = rbase + ii;
        if (rr < NODES) {
            float v = acc[8][ii];
            if (col < 8) as1[(size_t)rr * NHEAD + col] = v;
            else ad1[(size_t)rr * NHEAD + (col - 8)] = v;
        }
    }
}

// no-max softmax step, fp8 h-row (8 channels per lane)
#define PROC8F8(AV, HV)                                          \
    {                                                            \
        float l = (AV) + adv;                                    \
        l = l > 0.f ? l : 0.2f * l;                              \
        float p = __expf(l);                                     \
        den += p;                                                \
        f32x2 c0 = __builtin_amdgcn_cvt_pk_f32_fp8(HV.x, false); \
        f32x2 c1 = __builtin_amdgcn_cvt_pk_f32_fp8(HV.x, true);  \
        f32x2 c2 = __builtin_amdgcn_cvt_pk_f32_fp8(HV.y, false); \
        f32x2 c3 = __builtin_amdgcn_cvt_pk_f32_fp8(HV.y, true);  \
        acc[0] += p * c0.x; acc[1] += p * c0.y;                  \
        acc[2] += p * c1.x; acc[3] += p * c1.y;                  \
        acc[4] += p * c2.x; acc[5] += p * c2.y;                  \
        acc[6] += p * c3.x; acc[7] += p * c3.y;                  \
    }

// ---------- L1 gather + fused GEMM2: block owns 16 dst (M=16 tile) ----------
__global__ __launch_bounds__(256) void msg1g2(const int* __restrict__ fill,
                                              const unsigned short* __restrict__ csr16,
                                              const float* __restrict__ as1,
                                              const float* __restrict__ ad1,
                                              const unsigned char* __restrict__ h1f8,
                                              const float* __restrict__ b1,
                                              const unsigned short* __restrict__ W2e,
                                              unsigned char* __restrict__ h2f8,
                                              float* __restrict__ as2,
                                              float* __restrict__ ad2) {
    __shared__ uint4 w2s[768];           // 48 x 16 uint4 = 12 KB, swizzled
    __shared__ uint4 o1s[256];           // 16 rows x 16 uint4 = 4 KB, swizzled
    int t = threadIdx.x;
    int wid = t >> 6, lane = t & 63;
    int g = lane >> 4;                    // group 0..3 -> own dst
    int cl = lane & 15;                   // channel lane: ch 8*cl..8*cl+7
    int h = cl >> 1;                      // head

    // stage W2e (swizzled identically to gemm2m)
#pragma unroll
    for (int it = 0; it < 3; ++it) {
        int i = it * 256 + t;
        w2s[i ^ ((i >> 4) & 7)] = ((const uint4*)W2e)[i];
    }

    int d = blockIdx.x * 16 + wid * 4 + g;   // grid exact: 3125*16 = 50000
    float adv = ad1[(size_t)d * NHEAD + h];
    int deg = fill[d];                        // >= 1 (self loop)
    size_t eb = (size_t)d << 6;               // ELL row base
    float den = 0.f;
    float acc[8];
#pragma unroll
    for (int k = 0; k < 8; ++k) acc[k] = 0.f;

    const char* as1c = (const char*)as1;
    unsigned hoff = (unsigned)(h << 2);
    unsigned coff = (unsigned)(cl << 3);

// internal index j_ avoids shadowing the caller's loop variable (R11 bug)
#define LD1(J, AV, HV)                                                \
    {                                                                 \
        int j_ = (J);                                                 \
        AV = -1e30f; HV = make_uint2(0u, 0u);                         \
        if (j_ < deg) {                                               \
            unsigned ss = (unsigned)csr16[eb + j_];                   \
            AV = *(const float*)(as1c + (ss << 5) + hoff);            \
            HV = *(const uint2*)(h1f8 + (ss << 7) + coff);            \
        }                                                             \
    }

    float av0, av1; uint2 hv0, hv1;
    LD1(0, av0, hv0);
    LD1(1, av1, hv1);
    for (int j = 0; j < deg; j += 2) {
        float ta, tb; uint2 ua, ub;
        LD1(j + 2, ta, ua);
        LD1(j + 3, tb, ub);
        PROC8F8(av0, hv0);
        PROC8F8(av1, hv1);
        av0 = ta; hv0 = ua; av1 = tb; hv1 = ub;
    }
#undef LD1

    float invd = 1.f / (den + 1e-16f);
    const float4* bp = (const float4*)(b1 + cl * 8);
    float4 ba = bp[0], bb = bp[1];
    float v[8];
    v[0] = acc[0] * invd + ba.x; v[1] = acc[1] * invd + ba.y;
    v[2] = acc[2] * invd + ba.z; v[3] = acc[3] * invd + ba.w;
    v[4] = acc[4] * invd + bb.x; v[5] = acc[5] * invd + bb.y;
    v[6] = acc[6] * invd + bb.z; v[7] = acc[7] * invd + bb.w;
#pragma unroll
    for (int k = 0; k < 8; ++k) {
        float ev = __expf(v[k]) - 1.f;          // ELU negative branch
        v[k] = v[k] > 0.f ? v[k] : ev;
    }
    uint4 o;
    o.x = pk2(v[0], v[1]); o.y = pk2(v[2], v[3]);
    o.z = pk2(v[4], v[5]); o.w = pk2(v[6], v[7]);
    int orow = wid * 4 + g;
    o1s[(orow * 16 + cl) ^ (orow & 7)] = o;
    __syncthreads();

    // Phase 2: GEMM tile f = wid (waves 0..2), M=16 block dst, N=16, K=128
    if (wid < 3) {
        int r = lane & 15;
        int kg = lane >> 4;
        int swz = r & 7;
        f32x4 c2 = (f32x4){0.f, 0.f, 0.f, 0.f};
#pragma unroll
        for (int ks = 0; ks < 4; ++ks) {
            union { uint4 u; bf16x8 vv; } A, B;
            A.u = o1s[(r * 16 + kg + ks * 4) ^ swz];
            B.u = w2s[(wid * 256 + r * 16 + kg + ks * 4) ^ swz];
            c2 = __builtin_amdgcn_mfma_f32_16x16x32_bf16(A.vv, B.vv, c2, 0, 0, 0);
        }
        int col = lane & 15;
        int rbase = blockIdx.x * 16 + (lane >> 4) * 4;
        if (wid < 2) {
#pragma unroll
            for (int i = 0; i < 4; ++i)
                h2f8[(size_t)(rbase + i) * NC + wid * 16 + col] = f2fp8(c2[i]);
        } else {
            int c = 32 + col;
#pragma unroll
            for (int i = 0; i < 4; ++i) {
                int rr = rbase + i;
                if (c < NC) h2f8[(size_t)rr * NC + c] = f2fp8(c2[i]);
                else if (c == NC) as2[rr] = c2[i];
                else if (c == NC + 1) ad2[rr] = c2[i];
            }
        }
    }
}

// ---------- L2 gather: 8-lane group per dst (8 dst/wave), ELL, fp8 h2, depth-2 ----------
__global__ __launch_bounds__(256) void msg2(const int* __restrict__ fill,
                                            const unsigned short* __restrict__ csr16,
                                            const float* __restrict__ as2,
                                            const float* __restrict__ ad2,
                                            const unsigned char* __restrict__ h2f8,
                                            const float* __restrict__ b2,
                                            float* __restrict__ out) {
    int t = threadIdx.x;
    int wid = t >> 6, lane = t & 63;
    int g = lane >> 3;                    // group 0..7 -> own dst
    int cl = lane & 7;                    // channel lane; active cl<5 (8 ch each)
    int clc = cl < 5 ? cl : 4;
    bool act = cl < 5;
    int d0 = blockIdx.x * 32 + wid * 8 + g;
    int d = min(d0, NODES - 1);
    float adv = ad2[d];
    int deg = act ? fill[d] : 0;          // inactive lanes: no loads, no loop
    size_t eb = (size_t)d << 6;
    float den = 0.f;
    float acc[8];
#pragma unroll
    for (int k = 0; k < 8; ++k) acc[k] = 0.f;

    const char* as2c = (const char*)as2;
    unsigned coff = (unsigned)(clc << 3);

#define LD2(J, AV, HV)                                                \
    {                                                                 \
        int j_ = (J);                                                 \
        AV = -1e30f; HV = make_uint2(0u, 0u);                         \
        if (j_ < deg) {                                               \
            unsigned ss = (unsigned)csr16[eb + j_];                   \
            AV = *(const float*)(as2c + (ss << 2));                   \
            HV = *(const uint2*)(h2f8 + ss * 40u + coff);             \
        }                                                             \
    }

    float av0, av1; uint2 hv0, hv1;
    LD2(0, av0, hv0);
    LD2(1, av1, hv1);
    for (int j = 0; j < deg; j += 2) {
        float ta, tb; uint2 ua, ub;
        LD2(j + 2, ta, ua);
        LD2(j + 3, tb, ub);
        PROC8F8(av0, hv0);
        PROC8F8(av1, hv1);
        av0 = ta; hv0 = ua; av1 = tb; hv1 = ub;
    }
#undef LD2

    float invd = 1.f / (den + 1e-16f);
    float v[8];
    float mk = -1e30f;
    if (act) {
        const float4* bp = (const float4*)(b2 + cl * 8);
        float4 ba = bp[0], bb = bp[1];
        v[0] = acc[0] * invd + ba.x; v[1] = acc[1] * invd + ba.y;
        v[2] = acc[2] * invd + ba.z; v[3] = acc[3] * invd + ba.w;
        v[4] = acc[4] * invd + bb.x; v[5] = acc[5] * invd + bb.y;
        v[6] = acc[6] * invd + bb.z; v[7] = acc[7] * invd + bb.w;
#pragma unroll
        for (int k = 0; k < 8; ++k) mk = fmaxf(mk, v[k]);
    }
    // reduce within the 8-lane group
    mk = fmaxf(mk, __shfl_xor(mk, 1, 64));
    mk = fmaxf(mk, __shfl_xor(mk, 2, 64));
    mk = fmaxf(mk, __shfl_xor(mk, 4, 64));
    float e = 0.f;
    if (act) {
#pragma unroll
        for (int k = 0; k < 8; ++k) e += __expf(v[k] - mk);
    }
    e += __shfl_xor(e, 1, 64);
    e += __shfl_xor(e, 2, 64);
    e += __shfl_xor(e, 4, 64);
    float lse = mk + logf(e);
    if (act && d0 < NODES) {
        float4 o0 = make_float4(v[0] - lse, v[1] - lse, v[2] - lse, v[3] - lse);
        float4 o1 = make_float4(v[4] - lse, v[5] - lse, v[6] - lse, v[7] - lse);
        float* po = out + (size_t)d0 * NC + cl * 8;
        *(float4*)po = o0;
        *(float4*)(po + 4) = o1;
    }
}

extern "C" void kernel_launch(void* const* d_in, const int* in_sizes, int n_in,
                              void* d_out, int out_size, void* d_ws, size_t ws_size,
                              hipStream_t stream) {
    const float* x       = (const float*)d_in[0];
    const unsigned* eidx = (const unsigned*)d_in[1];
    const float* W1      = (const float*)d_in[2];
    const float* atts1   = (const float*)d_in[3];
    const float* attd1   = (const float*)d_in[4];
    const float* b1      = (const float*)d_in[5];
    const float* W2      = (const float*)d_in[6];
    const float* atts2   = (const float*)d_in[7];
    const float* attd2   = (const float*)d_in[8];
    const float* b2      = (const float*)d_in[9];
    float* out = (float*)d_out;

    char* base = (char*)d_ws;
    size_t off = 0;
    auto takeB = [&](size_t bytes) {
        void* p = base + off;
        off = (off + bytes + 255) & ~(size_t)255;
        return p;
    };
    int* fill      = (int*)takeB((size_t)NODES * 4);
    unsigned short* csr16 = (unsigned short*)takeB((size_t)NODES * ELLCAP * 2 + 256);
    unsigned short* W1t  = (unsigned short*)takeB((size_t)144 * NF * 2);
    unsigned short* W2e  = (unsigned short*)takeB((size_t)48 * F1 * 2);
    unsigned char* h1f8  = (unsigned char*)takeB((size_t)NODES * F1);
    float* as1     = (float*)takeB((size_t)NODES * NHEAD * 4);
    float* ad1     = (float*)takeB((size_t)NODES * NHEAD * 4);
    unsigned char* h2f8  = (unsigned char*)takeB((size_t)NODES * NC + 256);
    float* as2     = (float*)takeB((size_t)NODES * 4);
    float* ad2     = (float*)takeB((size_t)NODES * 4);

    hipMemsetAsync(fill, 0, (size_t)NODES * 4, stream);

    // weight prep (both layers, one dispatch)
    prepW12<<<192, 256, 0, stream>>>(W1, atts1, attd1, W2, atts2, attd2, W1t, W2e);

    // fused: ELL scatter (self-detecting) + layer-1 MFMA GEMM (fp8 h1 out)
    scatter_gemm1<<<SG_BLOCKS, 256, 0, stream>>>(eidx, fill, csr16,
                                                 x, W1t, h1f8, as1, ad1);

    // Layer-1 gather + fused layer-2 projection (out1 stays on-chip)
    msg1g2<<<NODES / 16, 256, 0, stream>>>(fill, csr16, as1, ad1, h1f8, b1,
                                           W2e, h2f8, as2, ad2);

    // Layer-2 gather + log_softmax
    msg2<<<(NODES + 31) / 32, 256, 0, stream>>>(fill, csr16, as2, ad2, h2f8, b2, out);
}